// Round 4
// baseline (904.737 us; speedup 1.0000x reference)
//
#include <hip/hip_runtime.h>
#include <hip/hip_bf16.h>

#define W_BIT 4
#define OUT_F 11008
#define IN_F 4096
#define KRANK 16
#define M_DIM 8192
#define QW_PLANE (OUT_F * IN_F / 8)

#define N_DIM OUT_F
#define K_DIM 4096
#define NT 64              // K tiles of 64
#define NBN 43             // N_DIM / 256

typedef __attribute__((ext_vector_type(8))) short short8;
typedef __attribute__((ext_vector_type(4))) float f32x4;

__device__ __forceinline__ short f2bf(float f) {
    union { float f; unsigned u; } v;
    v.f = f;
    unsigned r = v.u + 0x7fffu + ((v.u >> 16) & 1u);
    return (short)(r >> 16);
}

__device__ __forceinline__ void async16(void* lds_p, const void* g) {
    __builtin_amdgcn_global_load_lds(
        (const __attribute__((address_space(1))) unsigned int*)g,
        (__attribute__((address_space(3))) unsigned int*)lds_p,
        16, 0, 0);
}

#define BAR() __builtin_amdgcn_s_barrier()
#define LGKM0() do { asm volatile("s_waitcnt lgkmcnt(0)" ::: "memory"); \
                     __builtin_amdgcn_sched_barrier(0); } while (0)
#define VMC(n) do { asm volatile("s_waitcnt vmcnt(" #n ")" ::: "memory"); \
                    __builtin_amdgcn_sched_barrier(0); } while (0)
#define PRIO1() __builtin_amdgcn_s_setprio(1)
#define PRIO0() __builtin_amdgcn_s_setprio(0)

// ---------------------------------------------------------------------------
// Kernel 1: x fp32 -> bf16
// ---------------------------------------------------------------------------
__global__ __launch_bounds__(256) void convert_x_kernel(
    const float* __restrict__ x, short* __restrict__ xb) {
    int tid = blockIdx.x * blockDim.x + threadIdx.x;
    int stride = gridDim.x * blockDim.x;
    const int n8 = (M_DIM * IN_F) / 8;
    for (int i = tid; i < n8; i += stride) {
        f32x4 a = ((const f32x4*)x)[2 * i];
        f32x4 b = ((const f32x4*)x)[2 * i + 1];
        short8 o;
        o[0] = f2bf(a[0]); o[1] = f2bf(a[1]); o[2] = f2bf(a[2]); o[3] = f2bf(a[3]);
        o[4] = f2bf(b[0]); o[5] = f2bf(b[1]); o[6] = f2bf(b[2]); o[7] = f2bf(b[3]);
        ((short8*)xb)[i] = o;
    }
}

// ---------------------------------------------------------------------------
// Kernel 2: reconstruct w (unchanged from passing round)
// ---------------------------------------------------------------------------
__global__ __launch_bounds__(256) void reconstruct_w_kernel(
    const int* __restrict__ qw, const float* __restrict__ u,
    const float* __restrict__ vt, short* __restrict__ wb) {
    __shared__ float vts[W_BIT][KRANK][128];
    __shared__ float us[W_BIT][KRANK][64];

    const int t = threadIdx.x;
    const int o0 = blockIdx.y * 64;
    const int c0 = blockIdx.x * 128;

    for (int idx = t; idx < W_BIT * KRANK * 128; idx += 256) {
        int i = idx >> 11;
        int rem = idx & 2047;
        int k = rem >> 7;
        int c = rem & 127;
        vts[i][k][c] = vt[(i * KRANK + k) * IN_F + c0 + c];
    }
    for (int idx = t; idx < W_BIT * KRANK * 64; idx += 256) {
        int i = idx >> 10;
        int rem = idx & 1023;
        int o = rem >> 4;
        int k = rem & 15;
        us[i][k][o] = u[((size_t)i * OUT_F + o0 + o) * KRANK + k];
    }
    __syncthreads();

    const int to = (t >> 4) * 4;
    const int tc = (t & 15) * 8;

    float wacc[4][8];
#pragma unroll
    for (int r = 0; r < 4; ++r)
#pragma unroll
        for (int c = 0; c < 8; ++c) wacc[r][c] = 0.f;

#pragma unroll
    for (int i = 0; i < W_BIT; ++i) {
        float dot[4][8];
#pragma unroll
        for (int r = 0; r < 4; ++r)
#pragma unroll
            for (int c = 0; c < 8; ++c) dot[r][c] = 0.f;

#pragma unroll
        for (int k = 0; k < KRANK; ++k) {
            f32x4 uv = *(const f32x4*)&us[i][k][to];
            f32x4 v0 = *(const f32x4*)&vts[i][k][tc];
            f32x4 v1 = *(const f32x4*)&vts[i][k][tc + 4];
#pragma unroll
            for (int r = 0; r < 4; ++r) {
#pragma unroll
                for (int c = 0; c < 4; ++c) {
                    dot[r][c]     += uv[r] * v0[c];
                    dot[r][c + 4] += uv[r] * v1[c];
                }
            }
        }
#pragma unroll
        for (int r = 0; r < 4; ++r) {
            unsigned byte = (unsigned)qw[i * QW_PLANE + (((o0 + to + r) * IN_F + c0 + tc) >> 3)];
#pragma unroll
            for (int c = 0; c < 8; ++c) {
                wacc[r][c] += ((byte >> c) & 1u) ? dot[r][c] : -dot[r][c];
            }
        }
    }

#pragma unroll
    for (int r = 0; r < 4; ++r) {
        short8 o8;
#pragma unroll
        for (int c = 0; c < 8; ++c) o8[c] = f2bf(wacc[r][c]);
        *(short8*)&wb[(size_t)(o0 + to + r) * IN_F + c0 + tc] = o8;
    }
}

// ---------------------------------------------------------------------------
// Kernel 3: 256x256 tile, BK=64, 8 waves (2x4). m201-style 8-phase schedule
// with K-HALF slot granularity: LDS = 8 slots x 16 KiB (A[buf][kh], B[buf][kh],
// each 256 rows x 32 k-cols bf16). Every phase: {4-8 ds_read, 1 half-stage
// (2 global_load_lds), barrier, lgkmcnt(0), setprio+16 MFMA, barrier}.
// vmcnt(6) gates at ph2/ph4 of each K-tile; 5-6 phase stage lead.
// Swizzle: 16B-block index c ^= (row>>1)&3 within 64 B rows (both-sides).
// ---------------------------------------------------------------------------
__global__ __launch_bounds__(512, 2) void gemm256_kernel(
    const short* __restrict__ A, const short* __restrict__ B, float* __restrict__ C) {
    extern __shared__ short lds[];

    const int t = threadIdx.x;
    const int lane = t & 63, wid = t >> 6;
    const int wr = wid >> 2, wc = wid & 3;       // 2 x 4 wave grid
    const int fr = lane & 15, fq = lane >> 4;

    const int bid = blockIdx.x;
    const int cpx = gridDim.x >> 3;              // grid 1376 % 8 == 0
    const int swzb = (bid & 7) * cpx + (bid >> 3);
    const int bm = swzb / NBN, bn = swzb % NBN;
    const long row0 = (long)bm * 256, col0 = (long)bn * 256;

    // ---- fragment read bases (swizzled 16B-block; m/n-independent swizzle)
    const int colswz = (fq ^ ((fr >> 1) & 3)) * 8;          // shorts within 32-col row
    const int aoff = (wr * 128 + fr) * 32 + colswz;         // A region starts at 0
    const int boff = 32768 + (wc * 64 + fr) * 32 + colswz;  // B region at +32768 shorts

    // ---- staging: linear LDS dest, inverse-swizzled global source
    const int srow = t >> 2;                                 // 0..127
    const int sswz = (((t & 3) ^ ((srow >> 1) & 3)) << 3);   // shorts
    const short* pA0 = A + (row0 + srow) * (size_t)K_DIM + sswz;
    const short* pA1 = pA0 + (size_t)128 * K_DIM;
    const short* pB0 = B + (col0 + srow) * (size_t)K_DIM + sswz;
    const short* pB1 = pB0 + (size_t)128 * K_DIM;
    const int ldst0 = t * 8;                                 // shorts

    f32x4 acc[8][4];
#pragma unroll
    for (int m = 0; m < 8; ++m)
#pragma unroll
        for (int n = 0; n < 4; ++n) acc[m][n] = (f32x4)0.f;

    short8 af[4], bf0[4], bf1[4];

// stage one K-half slot: 2 x global_load_lds (rows srow and srow+128)
#define STG(P0, P1, SLOT, OFFB) do {                                   \
    async16(&lds[(SLOT) + ldst0], (const char*)(P0) + (OFFB));         \
    async16(&lds[(SLOT) + 4096 + ldst0], (const char*)(P1) + (OFFB));  \
} while (0)

// A-fragment reads: KSLOT = b*16384 + kh*8192 (absolute), MH = m-half 0/1
#define RDA(KSLOT, MH) do {                                            \
    _Pragma("unroll") for (int m = 0; m < 4; ++m)                      \
        af[m] = *(const short8*)&lds[(KSLOT) + ((MH) * 4 + m) * 512 + aoff]; \
} while (0)

// B-fragment reads: KSLOT relative to B region (boff carries +32768)
#define RDB(DST, KSLOT) do {                                           \
    _Pragma("unroll") for (int n = 0; n < 4; ++n)                      \
        DST[n] = *(const short8*)&lds[(KSLOT) + n * 512 + boff];       \
} while (0)

#define MFQ(BF, MH) do {                                               \
    _Pragma("unroll") for (int m = 0; m < 4; ++m)                      \
        _Pragma("unroll") for (int n = 0; n < 4; ++n)                  \
            acc[(MH) * 4 + m][n] = __builtin_amdgcn_mfma_f32_16x16x32_bf16( \
                af[m], BF[n], acc[(MH) * 4 + m][n], 0, 0, 0);          \
} while (0)

#define MMA(BF, MH) do { PRIO1(); MFQ(BF, MH); PRIO0(); } while (0)

    // ---- prologue: tile0 (kk0,kk32) + tile1 kk0 = 6 halves, 12 loads
    STG(pA0, pA1, 0,     0);    // A(0,kk0)  -> A[0][0]
    STG(pB0, pB1, 32768, 0);    // B(0,kk0)  -> B[0][0]
    STG(pA0, pA1, 8192,  64);   // A(0,kk32) -> A[0][1]
    STG(pB0, pB1, 40960, 64);   // B(0,kk32) -> B[0][1]
    STG(pA0, pA1, 16384, 128);  // A(1,kk0)  -> A[1][0]
    STG(pB0, pB1, 49152, 128);  // B(1,kk0)  -> B[1][0]
    VMC(8);                     // tile0 kk0 halves landed
    BAR();

    // ---- main loop: 31 iterations x 2 K-tiles (tiles 0..61)
    for (int it = 0; it < 31; ++it) {
        // == tile g (even, buf 0) ==
        // ph1: kk0, m0-3 | stage A(g+1,kk32) -> A[1][1]
        RDB(bf0, 0); RDA(0, 0);
        STG(pA0, pA1, 24576, 192);
        BAR(); LGKM0(); MMA(bf0, 0); BAR();
        // ph2: kk0, m4-7 | gate | stage B(g+1,kk32) -> B[1][1]
        RDA(0, 1);
        VMC(6);
        STG(pB0, pB1, 57344, 192);
        BAR(); LGKM0(); MMA(bf0, 1); BAR();
        // ph3: kk32, m0-3 | stage A(g+2,kk0) -> A[0][0]
        RDB(bf1, 8192); RDA(8192, 0);
        STG(pA0, pA1, 0, 256);
        BAR(); LGKM0(); MMA(bf1, 0); BAR();
        // ph4: kk32, m4-7 | gate | stage B(g+2,kk0) -> B[0][0]
        RDA(8192, 1);
        VMC(6);
        STG(pB0, pB1, 32768, 256);
        BAR(); LGKM0(); MMA(bf1, 1); BAR();

        // == tile g+1 (odd, buf 1) ==
        // ph5: kk0, m0-3 | stage A(g+2,kk32) -> A[0][1]
        RDB(bf0, 16384); RDA(16384, 0);
        STG(pA0, pA1, 8192, 320);
        BAR(); LGKM0(); MMA(bf0, 0); BAR();
        // ph6: kk0, m4-7 | gate | stage B(g+2,kk32) -> B[0][1]
        RDA(16384, 1);
        VMC(6);
        STG(pB0, pB1, 40960, 320);
        BAR(); LGKM0(); MMA(bf0, 1); BAR();
        // ph7: kk32, m0-3 | stage A(g+3,kk0) -> A[1][0]
        RDB(bf1, 24576); RDA(24576, 0);
        STG(pA0, pA1, 16384, 384);
        BAR(); LGKM0(); MMA(bf1, 0); BAR();
        // ph8: kk32, m4-7 | gate | stage B(g+3,kk0) -> B[1][0]
        RDA(24576, 1);
        VMC(6);
        STG(pB0, pB1, 49152, 384);
        BAR(); LGKM0(); MMA(bf1, 1); BAR();

        pA0 += 128; pA1 += 128; pB0 += 128; pB1 += 128;  // +256 B (2 K-tiles)
    }

    // ---- tail: tiles 62 (buf 0) and 63 (buf 1)
    // ph1: stage A(63,kk32) -> A[1][1]
    RDB(bf0, 0); RDA(0, 0);
    STG(pA0, pA1, 24576, 192);
    BAR(); LGKM0(); MMA(bf0, 0); BAR();
    // ph2: exact-count gate; stage B(63,kk32) -> B[1][1]
    RDA(0, 1);
    VMC(2);
    STG(pB0, pB1, 57344, 192);
    BAR(); LGKM0(); MMA(bf0, 1); BAR();
    // ph3
    RDB(bf1, 8192); RDA(8192, 0);
    BAR(); LGKM0(); MMA(bf1, 0); BAR();
    // ph4: drain everything (covers kk0(63) and kk32(63))
    RDA(8192, 1);
    VMC(0);
    BAR(); LGKM0(); MMA(bf1, 1); BAR();
    // tile 63, no stages/gates
    RDB(bf0, 16384); RDA(16384, 0);
    BAR(); LGKM0(); MMA(bf0, 0); BAR();
    RDA(16384, 1);
    BAR(); LGKM0(); MMA(bf0, 1); BAR();
    RDB(bf1, 24576); RDA(24576, 0);
    BAR(); LGKM0(); MMA(bf1, 0); BAR();
    RDA(24576, 1);
    BAR(); LGKM0(); MMA(bf1, 1); BAR();

    // ---- epilogue: C/D layout col = lane&15, row = (lane>>4)*4 + j
#pragma unroll
    for (int m = 0; m < 8; ++m) {
#pragma unroll
        for (int n = 0; n < 4; ++n) {
            f32x4 v = acc[m][n];
            long r0 = row0 + wr * 128 + m * 16 + fq * 4;
            long cc = col0 + wc * 64 + n * 16 + fr;
#pragma unroll
            for (int jj = 0; jj < 4; ++jj)
                C[(size_t)(r0 + jj) * N_DIM + cc] = v[jj];
        }
    }
#undef STG
#undef RDA
#undef RDB
#undef MFQ
#undef MMA
}

// ---------------------------------------------------------------------------
extern "C" void kernel_launch(void* const* d_in, const int* in_sizes, int n_in,
                              void* d_out, int out_size, void* d_ws, size_t ws_size,
                              hipStream_t stream) {
    const float* x  = (const float*)d_in[0];
    const int*   qw = (const int*)d_in[1];
    const float* u  = (const float*)d_in[2];
    const float* vt = (const float*)d_in[3];
    float* out = (float*)d_out;

    const size_t wb_bytes = (size_t)OUT_F * IN_F * 2;
    short* wb = (short*)d_ws;
    short* xb = (short*)((char*)d_ws + wb_bytes);

    (void)hipFuncSetAttribute((const void*)gemm256_kernel,
                              hipFuncAttributeMaxDynamicSharedMemorySize, 131072);

    hipLaunchKernelGGL(convert_x_kernel, dim3(2048), dim3(256), 0, stream, x, xb);
    hipLaunchKernelGGL(reconstruct_w_kernel, dim3(IN_F / 128, OUT_F / 64), dim3(256), 0, stream,
                       qw, u, vt, wb);
    hipLaunchKernelGGL(gemm256_kernel, dim3((M_DIM / 256) * (N_DIM / 256)), dim3(512), 131072,
                       stream, xb, wb, out);
}